// Round 13
// baseline (58.078 us; speedup 1.0000x reference)
//
#include <hip/hip_runtime.h>

// ---------------------------------------------------------------------------
// UpThreeOffsetsConvShareWeights v15: small-block ring -> 6 blocks/CU.
//
// Algebra unchanged (separable deform offsets -> per-phase 2x2x2-tap conv ==
// GEMM M=spatial x N=96 x K=512; fused K=96 combine GEMM), C^T convention,
// 32x32x16 MFMA, v5-proven W_sw/W2_sw layouts, v7-proven x-direct-from-L2
// (xT2 4-region, zero-tail OOB), drain-0 2-slot ring (proven), streaming
// cvt_pk+permlane epilogue, bf16-packed cp0 outputs, full-line float2 stores.
//
// v14 post-mortem: grid/tile mismatch (1024 blocks for a 512-block tiling)
// -> OOB stores -> abort. Also 4-wave/49KB blocks could never exceed
// 2 waves/SIMD at grid 512. v15 fixes both with one consistent geometry:
//  * block = 2 waves, tile (8x,4y,4z) = 128 spatial; 256 tiles x 4 phase
//    pairs = grid 1024 (decomposition closes: 1024*128*2 = 262144 outputs).
//  * ring = 2 slots x 12KB (1-tap chunks, 16 chunks); LDS 24.8KB/block ->
//    6 blocks/CU; launch_bounds(128,3) -> 170-reg cap -> 12 waves/CU.
//    16 drain-0 sync points now interleave across 6 independent blocks.
//  * register diet (v14): osv bf16-packed (16 regs), streaming per-nt
//    epilogue, biases via LDS table, w2 frags from global (L1-hot).
// ---------------------------------------------------------------------------

typedef __bf16 bf16x8 __attribute__((ext_vector_type(8)));
typedef float f32x16 __attribute__((ext_vector_type(16)));
typedef unsigned u32x2 __attribute__((ext_vector_type(2)));

__device__ inline unsigned short f2bf(float f) {
  unsigned int u = __float_as_uint(f);
  u += 0x7FFFu + ((u >> 16) & 1u);
  return (unsigned short)(u >> 16);
}

__device__ inline bf16x8 bc16(uint4 v) { return __builtin_bit_cast(bf16x8, v); }

__device__ inline unsigned cvtpk(float lo, float hi) {
  unsigned r;
  asm("v_cvt_pk_bf16_f32 %0, %1, %2" : "=v"(r) : "v"(lo), "v"(hi));
  return r;
}

__device__ inline void plswap(unsigned& a, unsigned& b) {
  u32x2 r = __builtin_amdgcn_permlane32_swap(a, b, false, false);
  a = r.x;
  b = r.y;
}

__device__ inline void gload16(const unsigned short* g, unsigned short* l) {
  __builtin_amdgcn_global_load_lds(
      (const __attribute__((address_space(1))) unsigned int*)(const void*)g,
      (__attribute__((address_space(3))) unsigned int*)(void*)l, 16, 0, 0);
}

__device__ inline float ucoef(int abit, int k, int jbit, float alpha) {
  if (abit == 0) return (k == 0) ? (jbit ? alpha : 1.f - alpha) : (jbit ? 1.f : 0.f);
  return (k == 2) ? (jbit ? 1.f - alpha : alpha) : (jbit ? 0.f : 1.f);
}

// xT2: 4 regions (16-ch groups), each 32768 sp * 32 B + 128 B zero tail.
#define XREG_USH 524352
#define XREG_B 1048704
#define XZERO_B 1048576u

// ---------------- K0: all preprocessing in one kernel (2049 blocks) ---------
// (byte-identical to v7/v14's proven k_prep)
__global__ void k_prep(const float* __restrict__ x, unsigned short* __restrict__ xT2,
                       const float* __restrict__ w_def, const float* __restrict__ bn1_g,
                       const float* __restrict__ bn1_v, unsigned short* __restrict__ W_sw,
                       const float* __restrict__ w_comb, const float* __restrict__ b_comb,
                       const float* __restrict__ bn2_g, const float* __restrict__ bn2_b,
                       const float* __restrict__ bn2_m, const float* __restrict__ bn2_v,
                       const float* __restrict__ b_def, const float* __restrict__ bn1_b,
                       const float* __restrict__ bn1_m, unsigned short* __restrict__ W2_sw,
                       float* __restrict__ bias1, float* __restrict__ bias2) {
  __shared__ unsigned short t[64][65];
  int bid = blockIdx.x;
  if (bid < 512) {
    int s0 = bid * 64;
    int lane = threadIdx.x & 63;
    int grp = threadIdx.x >> 6;
#pragma unroll
    for (int c = grp; c < 64; c += 4)
      t[c][lane] = f2bf(x[c * 32768 + s0 + lane]);
    __syncthreads();
    int q = lane >> 4, e = lane & 15;
#pragma unroll
    for (int s = grp; s < 64; s += 4)
      xT2[q * XREG_USH + (size_t)(s0 + s) * 16 + e] = t[lane][s];
  } else if (bid < 2048) {
    int e = (bid - 512) * 256 + threadIdx.x;  // < 393216
    int j = e & 7;
    int lane = (e >> 3) & 63;
    int idx = e >> 9;
    int nt = idx % 3;
    idx /= 3;
    int s = idx & 31;
    int p = idx >> 5;
    int o = lane & 31;
    int br = nt;
    int kk = 16 * s + ((lane >> 5) << 3) + j;
    int tap = kk >> 6, ch = kk & 63;
    int jz = (tap >> 2) & 1, jy = (tap >> 1) & 1, jx = tap & 1;
    int a = (p >> 2) & 1, b = (p >> 1) & 1, cp = p & 1;
    float alpha = (br == 0) ? 0.f : ((br == 1) ? 0.4f : 0.7f);
    const float* wb = w_def + (o * 64 + ch) * 27;
    float sum = 0.f;
    for (int kz = 0; kz < 3; ++kz) {
      float uz = ucoef(a, kz, jz, alpha);
      if (uz == 0.f) continue;
      for (int ky = 0; ky < 3; ++ky) {
        float uy = ucoef(b, ky, jy, alpha);
        if (uy == 0.f) continue;
        float uzy = uz * uy;
        for (int kx = 0; kx < 3; ++kx) {
          float ux = ucoef(cp, kx, jx, alpha);
          if (ux != 0.f) sum += wb[kz * 9 + ky * 3 + kx] * uzy * ux;
        }
      }
    }
    float s1 = bn1_g[o] * rsqrtf(bn1_v[o] + 1e-5f);
    W_sw[e] = f2bf(sum * s1);
  } else {
    int tid = threadIdx.x;
    for (int e = tid; e < 3072; e += 256) {
      int j = e & 7;
      int lane = (e >> 3) & 63;
      int s2 = e >> 9;
      int n = lane & 31;
      int k = 16 * s2 + ((lane >> 5) << 3) + j;
      float sc2 = bn2_g[n] * rsqrtf(bn2_v[n] + 1e-5f);
      W2_sw[e] = f2bf(w_comb[n * 96 + k] * sc2);
    }
    {
      int q = tid >> 6, e2 = tid & 63;
      xT2[q * XREG_USH + 524288 + e2] = 0;
    }
    if (tid < 32) {
      float s1 = bn1_g[tid] * rsqrtf(bn1_v[tid] + 1e-5f);
      bias1[tid] = (b_def[tid] - bn1_m[tid]) * s1 + bn1_b[tid];
      float s2 = bn2_g[tid] * rsqrtf(bn2_v[tid] + 1e-5f);
      bias2[tid] = (b_comb[tid] - bn2_m[tid]) * s2 + bn2_b[tid];
    }
  }
}

// ---------------- K1: main fused kernel -------------------------------------
// Grid 1024 blocks, 128 thr (2 waves). bid -> (a,bph) + (8x,4y,4z) tile,
// phase-siblings co-XCD. Wave wv covers z {i0+2wv, i0+2wv+1} (az = bit).
// M=64/wave: m=lane&31: ax=m&7, ay=(m>>3)&1, az=(m>>4)&1; mt = y-pair; h=lane>>5.
__launch_bounds__(128, 3)
__global__ void k_main(const unsigned short* __restrict__ xT2,
                       const unsigned short* __restrict__ W_sw,
                       const unsigned short* __restrict__ W2_sw,
                       const float* __restrict__ bias1f,
                       const float* __restrict__ bias2f,
                       float* __restrict__ out) {
  __shared__ unsigned short wring[2][6144];  // 2 slots * 12 KB (1 tap each)
  __shared__ float blds[64];                 // bias1 | bias2
  int tid = threadIdx.x;
  int lane = tid & 63;
  int wv = tid >> 6;  // 0..1
  int bid = blockIdx.x;
  int tb = (bid & 7) | ((bid >> 5) << 3);  // tile 0..255
  int ph = (bid >> 3) & 3;
  int bph = ph & 1, a = ph >> 1;
  int tx = tb & 3, ty = (tb >> 2) & 7, tz = tb >> 5;  // 4 x 8 x 8
  int i0 = tz * 4, j0 = ty * 4, k0 = tx * 8;

  if (tid < 32) {
    blds[tid] = bias1f[tid];
    blds[32 + tid] = bias2f[tid];
  }

  int m = lane & 31, h = lane >> 5;
  int ax = m & 7, ay = (m >> 3) & 1, az = (m >> 4) & 1;
  int p0 = (a << 2) | (bph << 1);
  int zbase = i0 + 2 * wv + az;
  const char* xb0 = (const char*)xT2 + (h << 4);

  // chunk c (0..15): phase p0|(c>>3), tap c&7 = 12288 B; 2 waves x 6144 B
  // each = 6 x width-16 wave-instructions.
  auto stage = [&](int c) {
    int pn = p0 | (c >> 3);
    const unsigned short* g =
        W_sw + pn * 49152 + (c & 7) * 6144 + wv * 3072 + lane * 8;
    unsigned short* l = &wring[c & 1][wv * 3072];
#pragma unroll
    for (int k = 0; k < 6; ++k) gload16(g + k * 512, l + k * 512);
  };

  __syncthreads();  // blds visible before loop barriers
  stage(0);

  unsigned osvp[2][8];  // cp=0 outputs, bf16-packed (ch pairs), per mt
  f32x16 acc[2][3];
#pragma unroll
  for (int mt = 0; mt < 2; ++mt)
#pragma unroll
    for (int nt = 0; nt < 3; ++nt) acc[mt][nt] = (f32x16)0.f;

  const uint4* w2q = (const uint4*)W2_sw + lane;

  for (int c = 0; c < 16; ++c) {
    asm volatile("s_waitcnt vmcnt(0)" ::: "memory");  // own chunk-c loads in
    __builtin_amdgcn_s_barrier();                     // both waves' parts in
    __builtin_amdgcn_sched_barrier(0);
    if (c < 15) stage(c + 1);  // next chunk flies during this chunk's work
    __builtin_amdgcn_sched_barrier(0);

    int cp = c >> 3, tap = c & 7;
    int jz = (tap >> 2) & 1, jy = (tap >> 1) & 1, jx = tap & 1;
    int gz = zbase + a - 1 + jz;
    int gx = k0 + ax + cp - 1 + jx;
    bool okzx = ((unsigned)gz < 32u) && ((unsigned)gx < 32u);
    unsigned xo[2];
#pragma unroll
    for (int mt = 0; mt < 2; ++mt) {
      int gy = j0 + 2 * mt + ay + bph - 1 + jy;
      bool ok = okzx && ((unsigned)gy < 32u);
      unsigned off = (unsigned)(((gz * 32 + gy) * 32 + gx) * 32);
      xo[mt] = ok ? off : XZERO_B;
    }

    const unsigned short* wfb = &wring[c & 1][lane * 8];
#pragma unroll
    for (int q = 0; q < 4; ++q) {  // s = 4*tap + q; region q of xT2
      const char* xp = xb0 + q * XREG_B;
      bf16x8 a0 = bc16(*(const uint4*)(xp + xo[0]));
      bf16x8 a1 = bc16(*(const uint4*)(xp + xo[1]));
      const unsigned short* wf = wfb + q * 1536;
      bf16x8 bb0 = bc16(*(const uint4*)(wf));
      bf16x8 bb1 = bc16(*(const uint4*)(wf + 512));
      bf16x8 bb2 = bc16(*(const uint4*)(wf + 1024));
      __builtin_amdgcn_s_setprio(1);
      acc[0][0] = __builtin_amdgcn_mfma_f32_32x32x16_bf16(bb0, a0, acc[0][0], 0, 0, 0);
      acc[1][0] = __builtin_amdgcn_mfma_f32_32x32x16_bf16(bb0, a1, acc[1][0], 0, 0, 0);
      acc[0][1] = __builtin_amdgcn_mfma_f32_32x32x16_bf16(bb1, a0, acc[0][1], 0, 0, 0);
      acc[1][1] = __builtin_amdgcn_mfma_f32_32x32x16_bf16(bb1, a1, acc[1][1], 0, 0, 0);
      acc[0][2] = __builtin_amdgcn_mfma_f32_32x32x16_bf16(bb2, a0, acc[0][2], 0, 0, 0);
      acc[1][2] = __builtin_amdgcn_mfma_f32_32x32x16_bf16(bb2, a1, acc[1][2], 0, 0, 0);
      __builtin_amdgcn_s_setprio(0);
    }

    if (c == 7) {
      // ---- cp=0 epilogue (streaming): BN1+ReLU -> frags -> combine MFMA
      //      -> BN2+ReLU -> bf16-pack into osvp ----
#pragma unroll
      for (int mt = 0; mt < 2; ++mt) {
        f32x16 acc2 = (f32x16)0.f;
#pragma unroll
        for (int nt = 0; nt < 3; ++nt) {
          unsigned ww[8];
#pragma unroll
          for (int qc = 0; qc < 8; ++qc) {
            int q = qc >> 1, c2 = qc & 1;
            int r0 = 4 * q + 2 * c2;
            int row = (r0 & 3) + ((r0 >> 2) << 3) + (h << 2);
            float lo = fmaxf(acc[mt][nt][r0] + blds[row], 0.f);
            float hi = fmaxf(acc[mt][nt][r0 + 1] + blds[row + 1], 0.f);
            ww[2 * q + c2] = cvtpk(lo, hi);
          }
          plswap(ww[0], ww[2]);
          plswap(ww[1], ww[3]);
          plswap(ww[4], ww[6]);
          plswap(ww[5], ww[7]);
          uint4 frA = make_uint4(ww[0], ww[1], ww[2], ww[3]);
          uint4 frB = make_uint4(ww[4], ww[5], ww[6], ww[7]);
          acc2 = __builtin_amdgcn_mfma_f32_32x32x16_bf16(bc16(w2q[(2 * nt) * 64]),
                                                         bc16(frA), acc2, 0, 0, 0);
          acc2 = __builtin_amdgcn_mfma_f32_32x32x16_bf16(bc16(w2q[(2 * nt + 1) * 64]),
                                                         bc16(frB), acc2, 0, 0, 0);
        }
#pragma unroll
        for (int w = 0; w < 8; ++w) {
          int r0 = 2 * w;
          int row = (r0 & 3) + ((r0 >> 2) << 3) + (h << 2);
          float o0 = fmaxf(acc2[r0] + blds[32 + row], 0.f);
          float o1 = fmaxf(acc2[r0 + 1] + blds[32 + row + 1], 0.f);
          osvp[mt][w] = cvtpk(o0, o1);
        }
#pragma unroll
        for (int nt = 0; nt < 3; ++nt) acc[mt][nt] = (f32x16)0.f;
      }
    }
  }

  // ---- cp=1 epilogue: same streaming pipeline + full-line float2 stores ----
#pragma unroll
  for (int mt = 0; mt < 2; ++mt) {
    f32x16 acc2 = (f32x16)0.f;
#pragma unroll
    for (int nt = 0; nt < 3; ++nt) {
      unsigned ww[8];
#pragma unroll
      for (int qc = 0; qc < 8; ++qc) {
        int q = qc >> 1, c2 = qc & 1;
        int r0 = 4 * q + 2 * c2;
        int row = (r0 & 3) + ((r0 >> 2) << 3) + (h << 2);
        float lo = fmaxf(acc[mt][nt][r0] + blds[row], 0.f);
        float hi = fmaxf(acc[mt][nt][r0 + 1] + blds[row + 1], 0.f);
        ww[2 * q + c2] = cvtpk(lo, hi);
      }
      plswap(ww[0], ww[2]);
      plswap(ww[1], ww[3]);
      plswap(ww[4], ww[6]);
      plswap(ww[5], ww[7]);
      uint4 frA = make_uint4(ww[0], ww[1], ww[2], ww[3]);
      uint4 frB = make_uint4(ww[4], ww[5], ww[6], ww[7]);
      acc2 = __builtin_amdgcn_mfma_f32_32x32x16_bf16(bc16(w2q[(2 * nt) * 64]),
                                                     bc16(frA), acc2, 0, 0, 0);
      acc2 = __builtin_amdgcn_mfma_f32_32x32x16_bf16(bc16(w2q[(2 * nt + 1) * 64]),
                                                     bc16(frB), acc2, 0, 0, 0);
    }
    int Z = 2 * zbase + a;
    int Y = 2 * (j0 + 2 * mt + ay) + bph;
    size_t sb = ((size_t)Z << 11) + (Y << 5) + (k0 + ax);
    float2* o2 = (float2*)out;
#pragma unroll
    for (int r = 0; r < 16; ++r) {
      int ch = (r & 3) + ((r >> 2) << 3) + (h << 2);
      float v1 = fmaxf(acc2[r] + blds[32 + ch], 0.f);
      unsigned pw = osvp[mt][r >> 1];
      float pv = __uint_as_float((r & 1) ? (pw & 0xffff0000u) : (pw << 16));
      o2[((size_t)ch << 17) + sb] = make_float2(pv, v1);
    }
  }
}

// ---------------------------------------------------------------------------
extern "C" void kernel_launch(void* const* d_in, const int* in_sizes, int n_in,
                              void* d_out, int out_size, void* d_ws, size_t ws_size,
                              hipStream_t stream) {
  (void)in_sizes; (void)n_in; (void)out_size; (void)ws_size;
  const float* x      = (const float*)d_in[0];
  const float* w_def  = (const float*)d_in[1];
  const float* b_def  = (const float*)d_in[2];
  const float* bn1_g  = (const float*)d_in[3];
  const float* bn1_b  = (const float*)d_in[4];
  const float* bn1_m  = (const float*)d_in[5];
  const float* bn1_v  = (const float*)d_in[6];
  const float* w_comb = (const float*)d_in[7];
  const float* b_comb = (const float*)d_in[8];
  const float* bn2_g  = (const float*)d_in[9];
  const float* bn2_b  = (const float*)d_in[10];
  const float* bn2_m  = (const float*)d_in[11];
  const float* bn2_v  = (const float*)d_in[12];

  char* ws = (char*)d_ws;
  unsigned short* xT2  = (unsigned short*)(ws);             // 4,194,816 B
  unsigned short* W_sw = (unsigned short*)(ws + 4194816);   //   786,432 B
  unsigned short* W2sw = (unsigned short*)(ws + 4981248);   //     6,144 B
  float* bias1 = (float*)(ws + 4987392);                    //       128 B
  float* bias2 = (float*)(ws + 4987520);                    //       128 B
  float* out = (float*)d_out;

  hipLaunchKernelGGL(k_prep, dim3(2049), dim3(256), 0, stream,
                     x, xT2, w_def, bn1_g, bn1_v, W_sw,
                     w_comb, b_comb, bn2_g, bn2_b, bn2_m, bn2_v,
                     b_def, bn1_b, bn1_m, W2sw, bias1, bias2);
  hipLaunchKernelGGL(k_main, dim3(1024), dim3(128), 0, stream,
                     xT2, W_sw, W2sw, bias1, bias2, out);
}

// Round 14
// 57.441 us; speedup vs baseline: 1.0111x; 1.0111x over previous
//
#include <hip/hip_runtime.h>

// ---------------------------------------------------------------------------
// UpThreeOffsetsConvShareWeights v16: whole-phase LDS weights, zero-sync loop.
//
// Algebra unchanged (separable deform offsets -> per-phase 2x2x2-tap conv ==
// GEMM M=spatial x N=96 x K=512; fused K=96 combine GEMM), C^T convention,
// 32x32x16 MFMA, v5-proven W_sw/W2_sw layouts, v7-proven xT2 4-region
// x-from-L2 (zero-tail OOB), v6-proven M=64 wave geometry and
// cvt_pk+permlane epilogue.
//
// Design-matrix gap: every 44-50us version had 8-16 in-loop vmcnt+barrier
// points (work 2.8k cy per 13.8k cy window); the barrier-free attempt (v9)
// failed only on weight traffic (per-wave L2 streams, dedup x2 -> 786MB).
// v16 = barrier-free AND block-shared weights:
//  * block = ONE phase x 8x8x8 tile (M=512). Phase weights = 96KB -> LDS,
//    staged once in the prologue (12 gload16/wave); ONE __syncthreads; then
//    the main loop has ZERO barriers / waits: 192 MFMA + 96 conflict-free
//    ds_read_b128 + 64 L2 x-loads per wave, fully compiler-scheduled.
//  * weight L2 traffic = 512 x 96KB = 49MB (lowest of any version).
//  * grid 512 = 64 tiles x 8 phases, bid&63 = tile -> XCD = tile%8: all 8
//    phase-siblings co-XCD -> 8x L2 reuse of the tile's x halo.
//  * no cp pairing -> scalar float stores (RMW accepted, ~1-2us; v2 data).
//    no osv (-32 regs). LDS 96.3KB -> 1 block/CU, 8 waves, 2 rounds.
// ---------------------------------------------------------------------------

typedef __bf16 bf16x8 __attribute__((ext_vector_type(8)));
typedef float f32x16 __attribute__((ext_vector_type(16)));
typedef unsigned u32x2 __attribute__((ext_vector_type(2)));

__device__ inline unsigned short f2bf(float f) {
  unsigned int u = __float_as_uint(f);
  u += 0x7FFFu + ((u >> 16) & 1u);
  return (unsigned short)(u >> 16);
}

__device__ inline bf16x8 bc16(uint4 v) { return __builtin_bit_cast(bf16x8, v); }

__device__ inline unsigned cvtpk(float lo, float hi) {
  unsigned r;
  asm("v_cvt_pk_bf16_f32 %0, %1, %2" : "=v"(r) : "v"(lo), "v"(hi));
  return r;
}

__device__ inline void plswap(unsigned& a, unsigned& b) {
  u32x2 r = __builtin_amdgcn_permlane32_swap(a, b, false, false);
  a = r.x;
  b = r.y;
}

__device__ inline void gload16(const unsigned short* g, unsigned short* l) {
  __builtin_amdgcn_global_load_lds(
      (const __attribute__((address_space(1))) unsigned int*)(const void*)g,
      (__attribute__((address_space(3))) unsigned int*)(void*)l, 16, 0, 0);
}

__device__ inline float ucoef(int abit, int k, int jbit, float alpha) {
  if (abit == 0) return (k == 0) ? (jbit ? alpha : 1.f - alpha) : (jbit ? 1.f : 0.f);
  return (k == 2) ? (jbit ? 1.f - alpha : alpha) : (jbit ? 0.f : 1.f);
}

// xT2: 4 regions (16-ch groups), each 32768 sp * 32 B + 128 B zero tail.
#define XREG_USH 524352
#define XREG_B 1048704
#define XZERO_B 1048576u

// ---------------- K0: all preprocessing in one kernel (2049 blocks) ---------
// (byte-identical to v7/v15's proven k_prep)
__global__ void k_prep(const float* __restrict__ x, unsigned short* __restrict__ xT2,
                       const float* __restrict__ w_def, const float* __restrict__ bn1_g,
                       const float* __restrict__ bn1_v, unsigned short* __restrict__ W_sw,
                       const float* __restrict__ w_comb, const float* __restrict__ b_comb,
                       const float* __restrict__ bn2_g, const float* __restrict__ bn2_b,
                       const float* __restrict__ bn2_m, const float* __restrict__ bn2_v,
                       const float* __restrict__ b_def, const float* __restrict__ bn1_b,
                       const float* __restrict__ bn1_m, unsigned short* __restrict__ W2_sw,
                       float* __restrict__ bias1, float* __restrict__ bias2) {
  __shared__ unsigned short t[64][65];
  int bid = blockIdx.x;
  if (bid < 512) {
    int s0 = bid * 64;
    int lane = threadIdx.x & 63;
    int grp = threadIdx.x >> 6;
#pragma unroll
    for (int c = grp; c < 64; c += 4)
      t[c][lane] = f2bf(x[c * 32768 + s0 + lane]);
    __syncthreads();
    int q = lane >> 4, e = lane & 15;
#pragma unroll
    for (int s = grp; s < 64; s += 4)
      xT2[q * XREG_USH + (size_t)(s0 + s) * 16 + e] = t[lane][s];
  } else if (bid < 2048) {
    int e = (bid - 512) * 256 + threadIdx.x;  // < 393216
    int j = e & 7;
    int lane = (e >> 3) & 63;
    int idx = e >> 9;
    int nt = idx % 3;
    idx /= 3;
    int s = idx & 31;
    int p = idx >> 5;
    int o = lane & 31;
    int br = nt;
    int kk = 16 * s + ((lane >> 5) << 3) + j;
    int tap = kk >> 6, ch = kk & 63;
    int jz = (tap >> 2) & 1, jy = (tap >> 1) & 1, jx = tap & 1;
    int a = (p >> 2) & 1, b = (p >> 1) & 1, cp = p & 1;
    float alpha = (br == 0) ? 0.f : ((br == 1) ? 0.4f : 0.7f);
    const float* wb = w_def + (o * 64 + ch) * 27;
    float sum = 0.f;
    for (int kz = 0; kz < 3; ++kz) {
      float uz = ucoef(a, kz, jz, alpha);
      if (uz == 0.f) continue;
      for (int ky = 0; ky < 3; ++ky) {
        float uy = ucoef(b, ky, jy, alpha);
        if (uy == 0.f) continue;
        float uzy = uz * uy;
        for (int kx = 0; kx < 3; ++kx) {
          float ux = ucoef(cp, kx, jx, alpha);
          if (ux != 0.f) sum += wb[kz * 9 + ky * 3 + kx] * uzy * ux;
        }
      }
    }
    float s1 = bn1_g[o] * rsqrtf(bn1_v[o] + 1e-5f);
    W_sw[e] = f2bf(sum * s1);
  } else {
    int tid = threadIdx.x;
    for (int e = tid; e < 3072; e += 256) {
      int j = e & 7;
      int lane = (e >> 3) & 63;
      int s2 = e >> 9;
      int n = lane & 31;
      int k = 16 * s2 + ((lane >> 5) << 3) + j;
      float sc2 = bn2_g[n] * rsqrtf(bn2_v[n] + 1e-5f);
      W2_sw[e] = f2bf(w_comb[n * 96 + k] * sc2);
    }
    {
      int q = tid >> 6, e2 = tid & 63;
      xT2[q * XREG_USH + 524288 + e2] = 0;
    }
    if (tid < 32) {
      float s1 = bn1_g[tid] * rsqrtf(bn1_v[tid] + 1e-5f);
      bias1[tid] = (b_def[tid] - bn1_m[tid]) * s1 + bn1_b[tid];
      float s2 = bn2_g[tid] * rsqrtf(bn2_v[tid] + 1e-5f);
      bias2[tid] = (b_comb[tid] - bn2_m[tid]) * s2 + bn2_b[tid];
    }
  }
}

// ---------------- K1: main fused kernel -------------------------------------
// Grid 512 blocks, 512 thr (8 waves). bid: tile = bid&63 (XCD = tile%8 ->
// phase-siblings co-XCD), phase p = bid>>6 (a,bph,cp). Tile = 8x8x8 input.
// Wave wv: zs=wv>>2, ys=wv&3. M=64/wave: m=lane&31: ax=m&7, ay=(m>>3)&1,
// az=m>>4; mt adds z+2. h=lane>>5. acc[mt][nt] f32x16 (C^T).
__launch_bounds__(512, 2)
__global__ void k_main(const unsigned short* __restrict__ xT2,
                       const unsigned short* __restrict__ W_sw,
                       const unsigned short* __restrict__ W2_sw,
                       const float* __restrict__ bias1f,
                       const float* __restrict__ bias2f,
                       float* __restrict__ out) {
  __shared__ unsigned short wlds[49152];  // whole phase: 96 KB
  __shared__ float blds[64];              // bias1 | bias2
  int tid = threadIdx.x;
  int lane = tid & 63;
  int wv = tid >> 6;  // 0..7
  int bid = blockIdx.x;
  int tb = bid & 63;      // tile (XCD = tb%8)
  int p = bid >> 6;       // phase 0..7
  int cp = p & 1, bph = (p >> 1) & 1, a = p >> 2;
  int tx = tb & 3, ty = (tb >> 2) & 3, tz = tb >> 4;  // 4x4x4 tiles of 8^3
  int i0 = tz * 8, j0 = ty * 8, k0 = tx * 8;

  // ---- prologue: stage phase weights (96 KB) + biases; ONE sync ----
  {
    const unsigned short* g = W_sw + (size_t)p * 49152 + wv * 6144 + lane * 8;
    unsigned short* l = wlds + wv * 6144;
#pragma unroll
    for (int k = 0; k < 12; ++k) gload16(g + k * 512, l + k * 512);
  }
  if (tid < 32) {
    blds[tid] = bias1f[tid];
    blds[32 + tid] = bias2f[tid];
  }
  __syncthreads();  // drains prologue VMEM; last sync in the kernel

  int m = lane & 31, h = lane >> 5;
  int ax = m & 7, ay = (m >> 3) & 1, az = m >> 4;
  int zs = wv >> 2, ys = wv & 3;
  int zin0 = i0 + 4 * zs + az;       // + 2*mt
  int yin = j0 + 2 * ys + ay;
  const char* xb0 = (const char*)xT2 + (h << 4);

  f32x16 acc[2][3];
#pragma unroll
  for (int mt = 0; mt < 2; ++mt)
#pragma unroll
    for (int nt = 0; nt < 3; ++nt) acc[mt][nt] = (f32x16)0.f;

  // ---- main loop: ZERO barriers / waits; compiler schedules freely ----
#pragma unroll
  for (int tap = 0; tap < 8; ++tap) {
    int jz = (tap >> 2) & 1, jy = (tap >> 1) & 1, jx = tap & 1;
    int gz0 = zin0 + a - 1 + jz;
    int gy = yin + bph - 1 + jy;
    int gx = k0 + ax + cp - 1 + jx;
    bool okyx = ((unsigned)gy < 32u) && ((unsigned)gx < 32u);
    unsigned xo[2];
#pragma unroll
    for (int mt = 0; mt < 2; ++mt) {
      int gz = gz0 + 2 * mt;
      bool ok = okyx && ((unsigned)gz < 32u);
      unsigned off = (unsigned)(((gz * 32 + gy) * 32 + gx) * 32);
      xo[mt] = ok ? off : XZERO_B;
    }
    const unsigned short* wfb = wlds + tap * 6144 + lane * 8;
#pragma unroll
    for (int q = 0; q < 4; ++q) {  // s = 4*tap + q; region q of xT2
      const char* xp = xb0 + q * XREG_B;
      bf16x8 a0 = bc16(*(const uint4*)(xp + xo[0]));
      bf16x8 a1 = bc16(*(const uint4*)(xp + xo[1]));
      const unsigned short* wf = wfb + q * 1536;
      bf16x8 bb0 = bc16(*(const uint4*)(wf));
      bf16x8 bb1 = bc16(*(const uint4*)(wf + 512));
      bf16x8 bb2 = bc16(*(const uint4*)(wf + 1024));
      acc[0][0] = __builtin_amdgcn_mfma_f32_32x32x16_bf16(bb0, a0, acc[0][0], 0, 0, 0);
      acc[1][0] = __builtin_amdgcn_mfma_f32_32x32x16_bf16(bb0, a1, acc[1][0], 0, 0, 0);
      acc[0][1] = __builtin_amdgcn_mfma_f32_32x32x16_bf16(bb1, a0, acc[0][1], 0, 0, 0);
      acc[1][1] = __builtin_amdgcn_mfma_f32_32x32x16_bf16(bb1, a1, acc[1][1], 0, 0, 0);
      acc[0][2] = __builtin_amdgcn_mfma_f32_32x32x16_bf16(bb2, a0, acc[0][2], 0, 0, 0);
      acc[1][2] = __builtin_amdgcn_mfma_f32_32x32x16_bf16(bb2, a1, acc[1][2], 0, 0, 0);
    }
  }

  // ---- epilogue: BN1+ReLU, cvt_pk+permlane relayout, combine, BN2+ReLU,
  //      scalar float stores (phase-exclusive output positions) ----
  const uint4* w2q = (const uint4*)W2_sw + lane;
#pragma unroll
  for (int mt = 0; mt < 2; ++mt) {
    f32x16 acc2 = (f32x16)0.f;
#pragma unroll
    for (int nt = 0; nt < 3; ++nt) {
      unsigned ww[8];
#pragma unroll
      for (int qc = 0; qc < 8; ++qc) {
        int q = qc >> 1, c2 = qc & 1;
        int r0 = 4 * q + 2 * c2;
        int row = (r0 & 3) + ((r0 >> 2) << 3) + (h << 2);
        float lo = fmaxf(acc[mt][nt][r0] + blds[row], 0.f);
        float hi = fmaxf(acc[mt][nt][r0 + 1] + blds[row + 1], 0.f);
        ww[2 * q + c2] = cvtpk(lo, hi);
      }
      plswap(ww[0], ww[2]);
      plswap(ww[1], ww[3]);
      plswap(ww[4], ww[6]);
      plswap(ww[5], ww[7]);
      uint4 frA = make_uint4(ww[0], ww[1], ww[2], ww[3]);
      uint4 frB = make_uint4(ww[4], ww[5], ww[6], ww[7]);
      acc2 = __builtin_amdgcn_mfma_f32_32x32x16_bf16(bc16(w2q[(2 * nt) * 64]),
                                                     bc16(frA), acc2, 0, 0, 0);
      acc2 = __builtin_amdgcn_mfma_f32_32x32x16_bf16(bc16(w2q[(2 * nt + 1) * 64]),
                                                     bc16(frB), acc2, 0, 0, 0);
    }
    int Z = 2 * (zin0 + 2 * mt) + a;
    int Y = 2 * yin + bph;
    int X = 2 * (k0 + ax) + cp;
    size_t sb = ((size_t)Z << 12) + (Y << 6) + X;
#pragma unroll
    for (int r = 0; r < 16; ++r) {
      int ch = (r & 3) + ((r >> 2) << 3) + (h << 2);
      out[((size_t)ch << 18) + sb] = fmaxf(acc2[r] + blds[32 + ch], 0.f);
    }
  }
}

// ---------------------------------------------------------------------------
extern "C" void kernel_launch(void* const* d_in, const int* in_sizes, int n_in,
                              void* d_out, int out_size, void* d_ws, size_t ws_size,
                              hipStream_t stream) {
  (void)in_sizes; (void)n_in; (void)out_size; (void)ws_size;
  const float* x      = (const float*)d_in[0];
  const float* w_def  = (const float*)d_in[1];
  const float* b_def  = (const float*)d_in[2];
  const float* bn1_g  = (const float*)d_in[3];
  const float* bn1_b  = (const float*)d_in[4];
  const float* bn1_m  = (const float*)d_in[5];
  const float* bn1_v  = (const float*)d_in[6];
  const float* w_comb = (const float*)d_in[7];
  const float* b_comb = (const float*)d_in[8];
  const float* bn2_g  = (const float*)d_in[9];
  const float* bn2_b  = (const float*)d_in[10];
  const float* bn2_m  = (const float*)d_in[11];
  const float* bn2_v  = (const float*)d_in[12];

  char* ws = (char*)d_ws;
  unsigned short* xT2  = (unsigned short*)(ws);             // 4,194,816 B
  unsigned short* W_sw = (unsigned short*)(ws + 4194816);   //   786,432 B
  unsigned short* W2sw = (unsigned short*)(ws + 4981248);   //     6,144 B
  float* bias1 = (float*)(ws + 4987392);                    //       128 B
  float* bias2 = (float*)(ws + 4987520);                    //       128 B
  float* out = (float*)d_out;

  hipLaunchKernelGGL(k_prep, dim3(2049), dim3(256), 0, stream,
                     x, xT2, w_def, bn1_g, bn1_v, W_sw,
                     w_comb, b_comb, bn2_g, bn2_b, bn2_m, bn2_v,
                     b_def, bn1_b, bn1_m, W2sw, bias1, bias2);
  hipLaunchKernelGGL(k_main, dim3(512), dim3(512), 0, stream,
                     xT2, W_sw, W2sw, bias1, bias2, out);
}

// Round 15
// 56.719 us; speedup vs baseline: 1.0240x; 1.0127x over previous
//
#include <hip/hip_runtime.h>

// ---------------------------------------------------------------------------
// UpThreeOffsetsConvShareWeights v17: v16 + explicit x register pipeline.
//
// Algebra unchanged (separable deform offsets -> per-phase 2x2x2-tap conv ==
// GEMM M=spatial x N=96 x K=512; fused K=96 combine GEMM), C^T convention,
// 32x32x16 MFMA, v5-proven W_sw/W2_sw layouts, v7-proven xT2 4-region
// x-from-L2 (zero-tail OOB), v16's zero-sync main loop (whole-phase 96KB
// weight LDS staged once; ONE __syncthreads in the kernel).
//
// v16 post-mortem: k_main 50->42 (best), MfmaUtil 25%. VGPR_Count=88 =>
// compiler holds only ~2-3 of the 8 per-tap x-loads in flight; each tap's
// 24 MFMAs stall on a ~300cy L2 x-load chain. TLP is reg-capped at
// 2 waves/SIMD (96-AGPR acc, structural: v8/v11/v15 alternatives all lost
// more than they gained), so v17 spends the idle 160 arch-VGPR headroom on
// ILP: explicit xA/xB ping-pong (tap t+1's 8 loads issued BEFORE tap t's
// MFMA cluster -> ~770cy of cover). Fully unrolled, all static indexing.
// ---------------------------------------------------------------------------

typedef __bf16 bf16x8 __attribute__((ext_vector_type(8)));
typedef float f32x16 __attribute__((ext_vector_type(16)));
typedef unsigned u32x2 __attribute__((ext_vector_type(2)));

__device__ inline unsigned short f2bf(float f) {
  unsigned int u = __float_as_uint(f);
  u += 0x7FFFu + ((u >> 16) & 1u);
  return (unsigned short)(u >> 16);
}

__device__ inline bf16x8 bc16(uint4 v) { return __builtin_bit_cast(bf16x8, v); }

__device__ inline unsigned cvtpk(float lo, float hi) {
  unsigned r;
  asm("v_cvt_pk_bf16_f32 %0, %1, %2" : "=v"(r) : "v"(lo), "v"(hi));
  return r;
}

__device__ inline void plswap(unsigned& a, unsigned& b) {
  u32x2 r = __builtin_amdgcn_permlane32_swap(a, b, false, false);
  a = r.x;
  b = r.y;
}

__device__ inline void gload16(const unsigned short* g, unsigned short* l) {
  __builtin_amdgcn_global_load_lds(
      (const __attribute__((address_space(1))) unsigned int*)(const void*)g,
      (__attribute__((address_space(3))) unsigned int*)(void*)l, 16, 0, 0);
}

__device__ inline float ucoef(int abit, int k, int jbit, float alpha) {
  if (abit == 0) return (k == 0) ? (jbit ? alpha : 1.f - alpha) : (jbit ? 1.f : 0.f);
  return (k == 2) ? (jbit ? 1.f - alpha : alpha) : (jbit ? 0.f : 1.f);
}

// xT2: 4 regions (16-ch groups), each 32768 sp * 32 B + 128 B zero tail.
#define XREG_USH 524352
#define XREG_B 1048704
#define XZERO_B 1048576u

// ---------------- K0: all preprocessing in one kernel (2049 blocks) ---------
// (byte-identical to v7/v16's proven k_prep)
__global__ void k_prep(const float* __restrict__ x, unsigned short* __restrict__ xT2,
                       const float* __restrict__ w_def, const float* __restrict__ bn1_g,
                       const float* __restrict__ bn1_v, unsigned short* __restrict__ W_sw,
                       const float* __restrict__ w_comb, const float* __restrict__ b_comb,
                       const float* __restrict__ bn2_g, const float* __restrict__ bn2_b,
                       const float* __restrict__ bn2_m, const float* __restrict__ bn2_v,
                       const float* __restrict__ b_def, const float* __restrict__ bn1_b,
                       const float* __restrict__ bn1_m, unsigned short* __restrict__ W2_sw,
                       float* __restrict__ bias1, float* __restrict__ bias2) {
  __shared__ unsigned short t[64][65];
  int bid = blockIdx.x;
  if (bid < 512) {
    int s0 = bid * 64;
    int lane = threadIdx.x & 63;
    int grp = threadIdx.x >> 6;
#pragma unroll
    for (int c = grp; c < 64; c += 4)
      t[c][lane] = f2bf(x[c * 32768 + s0 + lane]);
    __syncthreads();
    int q = lane >> 4, e = lane & 15;
#pragma unroll
    for (int s = grp; s < 64; s += 4)
      xT2[q * XREG_USH + (size_t)(s0 + s) * 16 + e] = t[lane][s];
  } else if (bid < 2048) {
    int e = (bid - 512) * 256 + threadIdx.x;  // < 393216
    int j = e & 7;
    int lane = (e >> 3) & 63;
    int idx = e >> 9;
    int nt = idx % 3;
    idx /= 3;
    int s = idx & 31;
    int p = idx >> 5;
    int o = lane & 31;
    int br = nt;
    int kk = 16 * s + ((lane >> 5) << 3) + j;
    int tap = kk >> 6, ch = kk & 63;
    int jz = (tap >> 2) & 1, jy = (tap >> 1) & 1, jx = tap & 1;
    int a = (p >> 2) & 1, b = (p >> 1) & 1, cp = p & 1;
    float alpha = (br == 0) ? 0.f : ((br == 1) ? 0.4f : 0.7f);
    const float* wb = w_def + (o * 64 + ch) * 27;
    float sum = 0.f;
    for (int kz = 0; kz < 3; ++kz) {
      float uz = ucoef(a, kz, jz, alpha);
      if (uz == 0.f) continue;
      for (int ky = 0; ky < 3; ++ky) {
        float uy = ucoef(b, ky, jy, alpha);
        if (uy == 0.f) continue;
        float uzy = uz * uy;
        for (int kx = 0; kx < 3; ++kx) {
          float ux = ucoef(cp, kx, jx, alpha);
          if (ux != 0.f) sum += wb[kz * 9 + ky * 3 + kx] * uzy * ux;
        }
      }
    }
    float s1 = bn1_g[o] * rsqrtf(bn1_v[o] + 1e-5f);
    W_sw[e] = f2bf(sum * s1);
  } else {
    int tid = threadIdx.x;
    for (int e = tid; e < 3072; e += 256) {
      int j = e & 7;
      int lane = (e >> 3) & 63;
      int s2 = e >> 9;
      int n = lane & 31;
      int k = 16 * s2 + ((lane >> 5) << 3) + j;
      float sc2 = bn2_g[n] * rsqrtf(bn2_v[n] + 1e-5f);
      W2_sw[e] = f2bf(w_comb[n * 96 + k] * sc2);
    }
    {
      int q = tid >> 6, e2 = tid & 63;
      xT2[q * XREG_USH + 524288 + e2] = 0;
    }
    if (tid < 32) {
      float s1 = bn1_g[tid] * rsqrtf(bn1_v[tid] + 1e-5f);
      bias1[tid] = (b_def[tid] - bn1_m[tid]) * s1 + bn1_b[tid];
      float s2 = bn2_g[tid] * rsqrtf(bn2_v[tid] + 1e-5f);
      bias2[tid] = (b_comb[tid] - bn2_m[tid]) * s2 + bn2_b[tid];
    }
  }
}

// ---------------- K1: main fused kernel -------------------------------------
// Grid 512 blocks, 512 thr (8 waves). bid: tile = bid&63 (XCD = tile%8 ->
// phase-siblings co-XCD), phase p = bid>>6 (a,bph,cp). Tile = 8x8x8 input.
// Wave wv: zs=wv>>2, ys=wv&3. M=64/wave. acc[mt][nt] f32x16 (C^T).
__launch_bounds__(512, 2)
__global__ void k_main(const unsigned short* __restrict__ xT2,
                       const unsigned short* __restrict__ W_sw,
                       const unsigned short* __restrict__ W2_sw,
                       const float* __restrict__ bias1f,
                       const float* __restrict__ bias2f,
                       float* __restrict__ out) {
  __shared__ unsigned short wlds[49152];  // whole phase: 96 KB
  __shared__ float blds[64];              // bias1 | bias2
  int tid = threadIdx.x;
  int lane = tid & 63;
  int wv = tid >> 6;  // 0..7
  int bid = blockIdx.x;
  int tb = bid & 63;      // tile (XCD = tb%8)
  int p = bid >> 6;       // phase 0..7
  int cp = p & 1, bph = (p >> 1) & 1, a = p >> 2;
  int tx = tb & 3, ty = (tb >> 2) & 3, tz = tb >> 4;  // 4x4x4 tiles of 8^3
  int i0 = tz * 8, j0 = ty * 8, k0 = tx * 8;

  // ---- prologue: stage phase weights (96 KB) + biases ----
  {
    const unsigned short* g = W_sw + (size_t)p * 49152 + wv * 6144 + lane * 8;
    unsigned short* l = wlds + wv * 6144;
#pragma unroll
    for (int k = 0; k < 12; ++k) gload16(g + k * 512, l + k * 512);
  }
  if (tid < 32) {
    blds[tid] = bias1f[tid];
    blds[32 + tid] = bias2f[tid];
  }

  int m = lane & 31, h = lane >> 5;
  int ax = m & 7, ay = (m >> 3) & 1, az = m >> 4;
  int zs = wv >> 2, ys = wv & 3;
  int zin0 = i0 + 4 * zs + az;  // + 2*mt
  int yin = j0 + 2 * ys + ay;
  const char* xb0 = (const char*)xT2 + (h << 4);

  // x loader: tap -> 8 uint4 (mt-major: dst[mt*4+q])
  auto ldx = [&](int tap, uint4* dst) {
    int jz = (tap >> 2) & 1, jy = (tap >> 1) & 1, jx = tap & 1;
    int gz0 = zin0 + a - 1 + jz;
    int gy = yin + bph - 1 + jy;
    int gx = k0 + ax + cp - 1 + jx;
    bool okyx = ((unsigned)gy < 32u) && ((unsigned)gx < 32u);
#pragma unroll
    for (int mt = 0; mt < 2; ++mt) {
      int gz = gz0 + 2 * mt;
      bool ok = okyx && ((unsigned)gz < 32u);
      unsigned off = (unsigned)(((gz * 32 + gy) * 32 + gx) * 32);
      unsigned xo = ok ? off : XZERO_B;
#pragma unroll
      for (int q = 0; q < 4; ++q)
        dst[mt * 4 + q] = *(const uint4*)(xb0 + q * XREG_B + xo);
    }
  };

  uint4 xA[8], xB[8];
  ldx(0, xA);       // tap-0 x in flight during the prologue drain
  __syncthreads();  // drains prologue VMEM; last sync in the kernel

  f32x16 acc[2][3];
#pragma unroll
  for (int mt = 0; mt < 2; ++mt)
#pragma unroll
    for (int nt = 0; nt < 3; ++nt) acc[mt][nt] = (f32x16)0.f;

  // ---- main loop: zero barriers; x ping-pong prefetched 1 tap ahead ----
#pragma unroll
  for (int tap = 0; tap < 8; ++tap) {
    uint4* cur = (tap & 1) ? xB : xA;
    uint4* nxt = (tap & 1) ? xA : xB;
    if (tap < 7) ldx(tap + 1, nxt);  // issue BEFORE this tap's MFMA cluster
    const unsigned short* wfb = wlds + tap * 6144 + lane * 8;
#pragma unroll
    for (int q = 0; q < 4; ++q) {  // s = 4*tap + q
      bf16x8 a0 = bc16(cur[q]);
      bf16x8 a1 = bc16(cur[4 + q]);
      const unsigned short* wf = wfb + q * 1536;
      bf16x8 bb0 = bc16(*(const uint4*)(wf));
      bf16x8 bb1 = bc16(*(const uint4*)(wf + 512));
      bf16x8 bb2 = bc16(*(const uint4*)(wf + 1024));
      acc[0][0] = __builtin_amdgcn_mfma_f32_32x32x16_bf16(bb0, a0, acc[0][0], 0, 0, 0);
      acc[1][0] = __builtin_amdgcn_mfma_f32_32x32x16_bf16(bb0, a1, acc[1][0], 0, 0, 0);
      acc[0][1] = __builtin_amdgcn_mfma_f32_32x32x16_bf16(bb1, a0, acc[0][1], 0, 0, 0);
      acc[1][1] = __builtin_amdgcn_mfma_f32_32x32x16_bf16(bb1, a1, acc[1][1], 0, 0, 0);
      acc[0][2] = __builtin_amdgcn_mfma_f32_32x32x16_bf16(bb2, a0, acc[0][2], 0, 0, 0);
      acc[1][2] = __builtin_amdgcn_mfma_f32_32x32x16_bf16(bb2, a1, acc[1][2], 0, 0, 0);
    }
  }

  // ---- epilogue: BN1+ReLU, cvt_pk+permlane relayout, combine, BN2+ReLU,
  //      scalar float stores (phase-exclusive output positions) ----
  const uint4* w2q = (const uint4*)W2_sw + lane;
#pragma unroll
  for (int mt = 0; mt < 2; ++mt) {
    f32x16 acc2 = (f32x16)0.f;
#pragma unroll
    for (int nt = 0; nt < 3; ++nt) {
      unsigned ww[8];
#pragma unroll
      for (int qc = 0; qc < 8; ++qc) {
        int q = qc >> 1, c2 = qc & 1;
        int r0 = 4 * q + 2 * c2;
        int row = (r0 & 3) + ((r0 >> 2) << 3) + (h << 2);
        float lo = fmaxf(acc[mt][nt][r0] + blds[row], 0.f);
        float hi = fmaxf(acc[mt][nt][r0 + 1] + blds[row + 1], 0.f);
        ww[2 * q + c2] = cvtpk(lo, hi);
      }
      plswap(ww[0], ww[2]);
      plswap(ww[1], ww[3]);
      plswap(ww[4], ww[6]);
      plswap(ww[5], ww[7]);
      uint4 frA = make_uint4(ww[0], ww[1], ww[2], ww[3]);
      uint4 frB = make_uint4(ww[4], ww[5], ww[6], ww[7]);
      acc2 = __builtin_amdgcn_mfma_f32_32x32x16_bf16(bc16(w2q[(2 * nt) * 64]),
                                                     bc16(frA), acc2, 0, 0, 0);
      acc2 = __builtin_amdgcn_mfma_f32_32x32x16_bf16(bc16(w2q[(2 * nt + 1) * 64]),
                                                     bc16(frB), acc2, 0, 0, 0);
    }
    int Z = 2 * (zin0 + 2 * mt) + a;
    int Y = 2 * yin + bph;
    int X = 2 * (k0 + ax) + cp;
    size_t sb = ((size_t)Z << 12) + (Y << 6) + X;
#pragma unroll
    for (int r = 0; r < 16; ++r) {
      int ch = (r & 3) + ((r >> 2) << 3) + (h << 2);
      out[((size_t)ch << 18) + sb] = fmaxf(acc2[r] + blds[32 + ch], 0.f);
    }
  }
}

// ---------------------------------------------------------------------------
extern "C" void kernel_launch(void* const* d_in, const int* in_sizes, int n_in,
                              void* d_out, int out_size, void* d_ws, size_t ws_size,
                              hipStream_t stream) {
  (void)in_sizes; (void)n_in; (void)out_size; (void)ws_size;
  const float* x      = (const float*)d_in[0];
  const float* w_def  = (const float*)d_in[1];
  const float* b_def  = (const float*)d_in[2];
  const float* bn1_g  = (const float*)d_in[3];
  const float* bn1_b  = (const float*)d_in[4];
  const float* bn1_m  = (const float*)d_in[5];
  const float* bn1_v  = (const float*)d_in[6];
  const float* w_comb = (const float*)d_in[7];
  const float* b_comb = (const float*)d_in[8];
  const float* bn2_g  = (const float*)d_in[9];
  const float* bn2_b  = (const float*)d_in[10];
  const float* bn2_m  = (const float*)d_in[11];
  const float* bn2_v  = (const float*)d_in[12];

  char* ws = (char*)d_ws;
  unsigned short* xT2  = (unsigned short*)(ws);             // 4,194,816 B
  unsigned short* W_sw = (unsigned short*)(ws + 4194816);   //   786,432 B
  unsigned short* W2sw = (unsigned short*)(ws + 4981248);   //     6,144 B
  float* bias1 = (float*)(ws + 4987392);                    //       128 B
  float* bias2 = (float*)(ws + 4987520);                    //       128 B
  float* out = (float*)d_out;

  hipLaunchKernelGGL(k_prep, dim3(2049), dim3(256), 0, stream,
                     x, xT2, w_def, bn1_g, bn1_v, W_sw,
                     w_comb, b_comb, bn2_g, bn2_b, bn2_m, bn2_v,
                     b_def, bn1_b, bn1_m, W2sw, bias1, bias2);
  hipLaunchKernelGGL(k_main, dim3(512), dim3(512), 0, stream,
                     xT2, W_sw, W2sw, bias1, bias2, out);
}

// Round 17
// 53.982 us; speedup vs baseline: 1.0759x; 1.0507x over previous
//
#include <hip/hip_runtime.h>

// ---------------------------------------------------------------------------
// UpThreeOffsetsConvShareWeights v18 (resubmit; r16 was an infra failure).
//
// Algebra unchanged (separable deform offsets -> per-phase 2x2x2-tap conv ==
// GEMM M=spatial x N=96 x K=512; fused K=96 combine GEMM), C^T convention,
// 32x32x16 MFMA, v5-proven W_sw/W2_sw layouts, v7-proven xT2 4-region
// x-from-L2 (zero-tail OOB), v16's zero-sync main loop (whole-phase 96KB
// weight LDS, ONE __syncthreads), v17's xA/xB 1-tap x prefetch.
//
// v17 post-mortem: profiled k_main at best (~40-42us) but total regressed vs
// v12 (52.65). Two attributable fixes:
//  * k_prep transpose wrote 32-B scattered chunks (lane split across 4
//    regions). v18: wave grp owns region grp, lane = sl*16+e -> every store
//    is a contiguous 128-B line (4x write coalescing).
//  * main loop lost setprio when syncs were removed; zero-sync free-running
//    waves are exactly the regime where T5 measured +4-7% (m191). Re-add
//    s_setprio(1/0) around each 6-MFMA q-cluster.
// Depth-2 x prefetch rejected: depth-1 cover (776cy) already > L2 latency,
// and +32 regs risks the 160-arch budget beside the 96-AGPR acc.
// ---------------------------------------------------------------------------

typedef __bf16 bf16x8 __attribute__((ext_vector_type(8)));
typedef float f32x16 __attribute__((ext_vector_type(16)));
typedef unsigned u32x2 __attribute__((ext_vector_type(2)));

__device__ inline unsigned short f2bf(float f) {
  unsigned int u = __float_as_uint(f);
  u += 0x7FFFu + ((u >> 16) & 1u);
  return (unsigned short)(u >> 16);
}

__device__ inline bf16x8 bc16(uint4 v) { return __builtin_bit_cast(bf16x8, v); }

__device__ inline unsigned cvtpk(float lo, float hi) {
  unsigned r;
  asm("v_cvt_pk_bf16_f32 %0, %1, %2" : "=v"(r) : "v"(lo), "v"(hi));
  return r;
}

__device__ inline void plswap(unsigned& a, unsigned& b) {
  u32x2 r = __builtin_amdgcn_permlane32_swap(a, b, false, false);
  a = r.x;
  b = r.y;
}

__device__ inline void gload16(const unsigned short* g, unsigned short* l) {
  __builtin_amdgcn_global_load_lds(
      (const __attribute__((address_space(1))) unsigned int*)(const void*)g,
      (__attribute__((address_space(3))) unsigned int*)(void*)l, 16, 0, 0);
}

__device__ inline float ucoef(int abit, int k, int jbit, float alpha) {
  if (abit == 0) return (k == 0) ? (jbit ? alpha : 1.f - alpha) : (jbit ? 1.f : 0.f);
  return (k == 2) ? (jbit ? 1.f - alpha : alpha) : (jbit ? 0.f : 1.f);
}

// xT2: 4 regions (16-ch groups), each 32768 sp * 32 B + 128 B zero tail.
#define XREG_USH 524352
#define XREG_B 1048704
#define XZERO_B 1048576u

// ---------------- K0: all preprocessing in one kernel (2049 blocks) ---------
__global__ void k_prep(const float* __restrict__ x, unsigned short* __restrict__ xT2,
                       const float* __restrict__ w_def, const float* __restrict__ bn1_g,
                       const float* __restrict__ bn1_v, unsigned short* __restrict__ W_sw,
                       const float* __restrict__ w_comb, const float* __restrict__ b_comb,
                       const float* __restrict__ bn2_g, const float* __restrict__ bn2_b,
                       const float* __restrict__ bn2_m, const float* __restrict__ bn2_v,
                       const float* __restrict__ b_def, const float* __restrict__ bn1_b,
                       const float* __restrict__ bn1_m, unsigned short* __restrict__ W2_sw,
                       float* __restrict__ bias1, float* __restrict__ bias2) {
  __shared__ unsigned short t[64][65];
  int bid = blockIdx.x;
  if (bid < 512) {
    int s0 = bid * 64;
    int lane = threadIdx.x & 63;
    int grp = threadIdx.x >> 6;
#pragma unroll
    for (int c = grp; c < 64; c += 4)
      t[c][lane] = f2bf(x[c * 32768 + s0 + lane]);
    __syncthreads();
    // coalesced writes: wave grp owns region grp; lane = sl*16 + e ->
    // each iteration stores one contiguous 128-B line.
    int e = lane & 15, sl = lane >> 4;
    unsigned short* dst = xT2 + (size_t)grp * XREG_USH + (size_t)s0 * 16;
#pragma unroll
    for (int sb = 0; sb < 64; sb += 4)
      dst[(sb + sl) * 16 + e] = t[grp * 16 + e][sb + sl];
  } else if (bid < 2048) {
    int e = (bid - 512) * 256 + threadIdx.x;  // < 393216
    int j = e & 7;
    int lane = (e >> 3) & 63;
    int idx = e >> 9;
    int nt = idx % 3;
    idx /= 3;
    int s = idx & 31;
    int p = idx >> 5;
    int o = lane & 31;
    int br = nt;
    int kk = 16 * s + ((lane >> 5) << 3) + j;
    int tap = kk >> 6, ch = kk & 63;
    int jz = (tap >> 2) & 1, jy = (tap >> 1) & 1, jx = tap & 1;
    int a = (p >> 2) & 1, b = (p >> 1) & 1, cp = p & 1;
    float alpha = (br == 0) ? 0.f : ((br == 1) ? 0.4f : 0.7f);
    const float* wb = w_def + (o * 64 + ch) * 27;
    float sum = 0.f;
    for (int kz = 0; kz < 3; ++kz) {
      float uz = ucoef(a, kz, jz, alpha);
      if (uz == 0.f) continue;
      for (int ky = 0; ky < 3; ++ky) {
        float uy = ucoef(b, ky, jy, alpha);
        if (uy == 0.f) continue;
        float uzy = uz * uy;
        for (int kx = 0; kx < 3; ++kx) {
          float ux = ucoef(cp, kx, jx, alpha);
          if (ux != 0.f) sum += wb[kz * 9 + ky * 3 + kx] * uzy * ux;
        }
      }
    }
    float s1 = bn1_g[o] * rsqrtf(bn1_v[o] + 1e-5f);
    W_sw[e] = f2bf(sum * s1);
  } else {
    int tid = threadIdx.x;
    for (int e = tid; e < 3072; e += 256) {
      int j = e & 7;
      int lane = (e >> 3) & 63;
      int s2 = e >> 9;
      int n = lane & 31;
      int k = 16 * s2 + ((lane >> 5) << 3) + j;
      float sc2 = bn2_g[n] * rsqrtf(bn2_v[n] + 1e-5f);
      W2_sw[e] = f2bf(w_comb[n * 96 + k] * sc2);
    }
    {
      int q = tid >> 6, e2 = tid & 63;
      xT2[q * XREG_USH + 524288 + e2] = 0;
    }
    if (tid < 32) {
      float s1 = bn1_g[tid] * rsqrtf(bn1_v[tid] + 1e-5f);
      bias1[tid] = (b_def[tid] - bn1_m[tid]) * s1 + bn1_b[tid];
      float s2 = bn2_g[tid] * rsqrtf(bn2_v[tid] + 1e-5f);
      bias2[tid] = (b_comb[tid] - bn2_m[tid]) * s2 + bn2_b[tid];
    }
  }
}

// ---------------- K1: main fused kernel -------------------------------------
// Grid 512 blocks, 512 thr (8 waves). bid: tile = bid&63 (XCD = tile%8 ->
// phase-siblings co-XCD), phase p = bid>>6 (a,bph,cp). Tile = 8x8x8 input.
// Wave wv: zs=wv>>2, ys=wv&3. M=64/wave. acc[mt][nt] f32x16 (C^T).
__launch_bounds__(512, 2)
__global__ void k_main(const unsigned short* __restrict__ xT2,
                       const unsigned short* __restrict__ W_sw,
                       const unsigned short* __restrict__ W2_sw,
                       const float* __restrict__ bias1f,
                       const float* __restrict__ bias2f,
                       float* __restrict__ out) {
  __shared__ unsigned short wlds[49152];  // whole phase: 96 KB
  __shared__ float blds[64];              // bias1 | bias2
  int tid = threadIdx.x;
  int lane = tid & 63;
  int wv = tid >> 6;  // 0..7
  int bid = blockIdx.x;
  int tb = bid & 63;      // tile (XCD = tb%8)
  int p = bid >> 6;       // phase 0..7
  int cp = p & 1, bph = (p >> 1) & 1, a = p >> 2;
  int tx = tb & 3, ty = (tb >> 2) & 3, tz = tb >> 4;  // 4x4x4 tiles of 8^3
  int i0 = tz * 8, j0 = ty * 8, k0 = tx * 8;

  // ---- prologue: stage phase weights (96 KB) + biases ----
  {
    const unsigned short* g = W_sw + (size_t)p * 49152 + wv * 6144 + lane * 8;
    unsigned short* l = wlds + wv * 6144;
#pragma unroll
    for (int k = 0; k < 12; ++k) gload16(g + k * 512, l + k * 512);
  }
  if (tid < 32) {
    blds[tid] = bias1f[tid];
    blds[32 + tid] = bias2f[tid];
  }

  int m = lane & 31, h = lane >> 5;
  int ax = m & 7, ay = (m >> 3) & 1, az = m >> 4;
  int zs = wv >> 2, ys = wv & 3;
  int zin0 = i0 + 4 * zs + az;  // + 2*mt
  int yin = j0 + 2 * ys + ay;
  const char* xb0 = (const char*)xT2 + (h << 4);

  // x loader: tap -> 8 uint4 (mt-major: dst[mt*4+q])
  auto ldx = [&](int tap, uint4* dst) {
    int jz = (tap >> 2) & 1, jy = (tap >> 1) & 1, jx = tap & 1;
    int gz0 = zin0 + a - 1 + jz;
    int gy = yin + bph - 1 + jy;
    int gx = k0 + ax + cp - 1 + jx;
    bool okyx = ((unsigned)gy < 32u) && ((unsigned)gx < 32u);
#pragma unroll
    for (int mt = 0; mt < 2; ++mt) {
      int gz = gz0 + 2 * mt;
      bool ok = okyx && ((unsigned)gz < 32u);
      unsigned off = (unsigned)(((gz * 32 + gy) * 32 + gx) * 32);
      unsigned xo = ok ? off : XZERO_B;
#pragma unroll
      for (int q = 0; q < 4; ++q)
        dst[mt * 4 + q] = *(const uint4*)(xb0 + q * XREG_B + xo);
    }
  };

  uint4 xA[8], xB[8];
  ldx(0, xA);       // tap-0 x in flight during the prologue drain
  __syncthreads();  // drains prologue VMEM; last sync in the kernel

  f32x16 acc[2][3];
#pragma unroll
  for (int mt = 0; mt < 2; ++mt)
#pragma unroll
    for (int nt = 0; nt < 3; ++nt) acc[mt][nt] = (f32x16)0.f;

  // ---- main loop: zero barriers; x ping-pong prefetched 1 tap ahead ----
#pragma unroll
  for (int tap = 0; tap < 8; ++tap) {
    uint4* cur = (tap & 1) ? xB : xA;
    uint4* nxt = (tap & 1) ? xA : xB;
    if (tap < 7) ldx(tap + 1, nxt);  // issue BEFORE this tap's MFMA cluster
    const unsigned short* wfb = wlds + tap * 6144 + lane * 8;
#pragma unroll
    for (int q = 0; q < 4; ++q) {  // s = 4*tap + q
      bf16x8 a0 = bc16(cur[q]);
      bf16x8 a1 = bc16(cur[4 + q]);
      const unsigned short* wf = wfb + q * 1536;
      bf16x8 bb0 = bc16(*(const uint4*)(wf));
      bf16x8 bb1 = bc16(*(const uint4*)(wf + 512));
      bf16x8 bb2 = bc16(*(const uint4*)(wf + 1024));
      __builtin_amdgcn_s_setprio(1);
      acc[0][0] = __builtin_amdgcn_mfma_f32_32x32x16_bf16(bb0, a0, acc[0][0], 0, 0, 0);
      acc[1][0] = __builtin_amdgcn_mfma_f32_32x32x16_bf16(bb0, a1, acc[1][0], 0, 0, 0);
      acc[0][1] = __builtin_amdgcn_mfma_f32_32x32x16_bf16(bb1, a0, acc[0][1], 0, 0, 0);
      acc[1][1] = __builtin_amdgcn_mfma_f32_32x32x16_bf16(bb1, a1, acc[1][1], 0, 0, 0);
      acc[0][2] = __builtin_amdgcn_mfma_f32_32x32x16_bf16(bb2, a0, acc[0][2], 0, 0, 0);
      acc[1][2] = __builtin_amdgcn_mfma_f32_32x32x16_bf16(bb2, a1, acc[1][2], 0, 0, 0);
      __builtin_amdgcn_s_setprio(0);
    }
  }

  // ---- epilogue: BN1+ReLU, cvt_pk+permlane relayout, combine, BN2+ReLU,
  //      scalar float stores (phase-exclusive output positions) ----
  const uint4* w2q = (const uint4*)W2_sw + lane;
#pragma unroll
  for (int mt = 0; mt < 2; ++mt) {
    f32x16 acc2 = (f32x16)0.f;
#pragma unroll
    for (int nt = 0; nt < 3; ++nt) {
      unsigned ww[8];
#pragma unroll
      for (int qc = 0; qc < 8; ++qc) {
        int q = qc >> 1, c2 = qc & 1;
        int r0 = 4 * q + 2 * c2;
        int row = (r0 & 3) + ((r0 >> 2) << 3) + (h << 2);
        float lo = fmaxf(acc[mt][nt][r0] + blds[row], 0.f);
        float hi = fmaxf(acc[mt][nt][r0 + 1] + blds[row + 1], 0.f);
        ww[2 * q + c2] = cvtpk(lo, hi);
      }
      plswap(ww[0], ww[2]);
      plswap(ww[1], ww[3]);
      plswap(ww[4], ww[6]);
      plswap(ww[5], ww[7]);
      uint4 frA = make_uint4(ww[0], ww[1], ww[2], ww[3]);
      uint4 frB = make_uint4(ww[4], ww[5], ww[6], ww[7]);
      acc2 = __builtin_amdgcn_mfma_f32_32x32x16_bf16(bc16(w2q[(2 * nt) * 64]),
                                                     bc16(frA), acc2, 0, 0, 0);
      acc2 = __builtin_amdgcn_mfma_f32_32x32x16_bf16(bc16(w2q[(2 * nt + 1) * 64]),
                                                     bc16(frB), acc2, 0, 0, 0);
    }
    int Z = 2 * (zin0 + 2 * mt) + a;
    int Y = 2 * yin + bph;
    int X = 2 * (k0 + ax) + cp;
    size_t sb = ((size_t)Z << 12) + (Y << 6) + X;
#pragma unroll
    for (int r = 0; r < 16; ++r) {
      int ch = (r & 3) + ((r >> 2) << 3) + (h << 2);
      out[((size_t)ch << 18) + sb] = fmaxf(acc2[r] + blds[32 + ch], 0.f);
    }
  }
}

// ---------------------------------------------------------------------------
extern "C" void kernel_launch(void* const* d_in, const int* in_sizes, int n_in,
                              void* d_out, int out_size, void* d_ws, size_t ws_size,
                              hipStream_t stream) {
  (void)in_sizes; (void)n_in; (void)out_size; (void)ws_size;
  const float* x      = (const float*)d_in[0];
  const float* w_def  = (const float*)d_in[1];
  const float* b_def  = (const float*)d_in[2];
  const float* bn1_g  = (const float*)d_in[3];
  const float* bn1_b  = (const float*)d_in[4];
  const float* bn1_m  = (const float*)d_in[5];
  const float* bn1_v  = (const float*)d_in[6];
  const float* w_comb = (const float*)d_in[7];
  const float* b_comb = (const float*)d_in[8];
  const float* bn2_g  = (const float*)d_in[9];
  const float* bn2_b  = (const float*)d_in[10];
  const float* bn2_m  = (const float*)d_in[11];
  const float* bn2_v  = (const float*)d_in[12];

  char* ws = (char*)d_ws;
  unsigned short* xT2  = (unsigned short*)(ws);             // 4,194,816 B
  unsigned short* W_sw = (unsigned short*)(ws + 4194816);   //   786,432 B
  unsigned short* W2sw = (unsigned short*)(ws + 4981248);   //     6,144 B
  float* bias1 = (float*)(ws + 4987392);                    //       128 B
  float* bias2 = (float*)(ws + 4987520);                    //       128 B
  float* out = (float*)d_out;

  hipLaunchKernelGGL(k_prep, dim3(2049), dim3(256), 0, stream,
                     x, xT2, w_def, bn1_g, bn1_v, W_sw,
                     w_comb, b_comb, bn2_g, bn2_b, bn2_m, bn2_v,
                     b_def, bn1_b, bn1_m, W2sw, bias1, bias2);
  hipLaunchKernelGGL(k_main, dim3(512), dim3(512), 0, stream,
                     xT2, W_sw, W2sw, bias1, bias2, out);
}